// Round 12
// baseline (138.358 us; speedup 1.0000x reference)
//
#include <hip/hip_runtime.h>

typedef unsigned short u16;
typedef unsigned int u32;
typedef unsigned long long u64;
typedef __bf16 bf16x8 __attribute__((ext_vector_type(8)));
typedef float f32x4 __attribute__((ext_vector_type(4)));

__device__ __forceinline__ u16 f2bf(float f) {
  u32 u = __float_as_uint(f);
  return (u16)((u + 0x7fffu + ((u >> 16) & 1u)) >> 16);  // RNE
}
__device__ __forceinline__ float bf2f(u16 h) {
  return __uint_as_float(((u32)h) << 16);
}
// packed f32x2 -> bf16x2 (one instruction, RNE)
__device__ __forceinline__ u32 pkbf(float lo, float hi) {
  u32 r;
  asm("v_cvt_pk_bf16_f32 %0, %1, %2" : "=v"(r) : "v"(lo), "v"(hi));
  return r;
}

// async global->LDS, 16B per lane; LDS dest = wave-uniform base + lane*16,
// global src is PER-LANE (verified R5/R6)
__device__ __forceinline__ void glds16(const void* g, void* s) {
  __builtin_amdgcn_global_load_lds(
      (__attribute__((address_space(1))) void*)(u64)g,
      (__attribute__((address_space(3))) void*)(u32)(u64)s, 16, 0, 0);
}

// ---------------- weight prep ----------------
__global__ __launch_bounds__(256) void k_prep_w(
    const float* __restrict__ Wq, const float* __restrict__ bq,
    const float* __restrict__ Wkv, const float* __restrict__ bkv,
    const float* __restrict__ Wproj,
    u16* __restrict__ W1t, float* __restrict__ b1, u16* __restrict__ Wpt) {
  int n = blockIdx.x, k = threadIdx.x;
  if (n < 768) {
    float v = (n < 256) ? Wq[k * 256 + n] * 0.125f : Wkv[k * 512 + (n - 256)];
    W1t[n * 256 + k] = f2bf(v);
    if (k == 0) b1[n] = (n < 256) ? bq[n] * 0.125f : bkv[n - 256];
  } else {
    int nn = n - 768;
    Wpt[nn * 256 + k] = f2bf(Wproj[k * 256 + nn]);
  }
}

// ---------------- GEMM1 fused: QKV[M x 768] = cvt_bf16(x[M x 256]) * W1t^T + b1 ----
// 256x128 tile, BK=64, 8 waves, 512 threads. R10 staging (reg cvt + swizzled
// ds_write for A, glds16 for B). SWAPPED-OPERAND MFMA: acc = mfma(B, A, acc)
// => per lane D holds fixed C-row (m*16 + (lane&15)) and 4 CONSECUTIVE C-cols
// (n*16 + (lane>>4)*4 + rr) -> packed uint2 stores (8B/lane) in the epilogue.
__global__ __launch_bounds__(512) void k_gemm1f(const float* __restrict__ A,
                                                const u16* __restrict__ Bt,
                                                const float* __restrict__ bias,
                                                u16* __restrict__ Cout) {
  __shared__ u16 As[256 * 64];   // 32 KB
  __shared__ u16 Bs[128 * 64];   // 16 KB
  const int N = 768, nt = 6;
  int nwg = gridDim.x;
  int bid = blockIdx.x;
  int swz = (bid & 7) * (nwg >> 3) + (bid >> 3);
  int mt = swz / nt;
  int ntile = swz - mt * nt;
  int tid = threadIdx.x;
  int lane = tid & 63, wid = tid >> 6;
  int wm = wid >> 1, wn = wid & 1;
  size_t mbase = (size_t)mt << 8;
  int nbase = ntile << 7;

  // B staging source (pre-swizzled chunk)
  int srow = lane >> 3;
  u32 schunk = ((u32)(lane & 7)) ^ ((u32)srow);
  const u16* bgS = Bt + ((size_t)(nbase + wid * 16 + srow)) * 256 + schunk * 8;

  // A staging coords: thread -> (chunk sc, base row sr0); 4 row-groups of 64
  int sc = tid & 7;
  int sr0 = tid >> 3;            // 0..63
  u32 aslot = (((u32)sc ^ ((u32)sr0 & 7)) * 16);   // swizzled byte slot
  const float* agS = A + (mbase + (size_t)sr0) * 256 + sc * 8;

  f32x4 acc[4][4] = {};

#pragma unroll
  for (int kb = 0; kb < 4; ++kb) {
    __syncthreads();   // previous round's readers done
    // stage B (glds16, swizzled source)
#pragma unroll
    for (int it = 0; it < 2; ++it)
      glds16(bgS + (size_t)(it * 8) * 256 + kb * 64, Bs + (wid * 16 + it * 8) * 64);
    // stage A: fp32 -> bf16 in regs -> swizzled ds_write_b128
#pragma unroll
    for (int rp = 0; rp < 4; ++rp) {
      const float* src = agS + (size_t)(rp * 64) * 256 + kb * 64;
      float4 f0 = *(const float4*)(src);
      float4 f1 = *(const float4*)(src + 4);
      uint4 val;
      val.x = pkbf(f0.x, f0.y);
      val.y = pkbf(f0.z, f0.w);
      val.z = pkbf(f1.x, f1.y);
      val.w = pkbf(f1.z, f1.w);
      *(uint4*)((char*)As + (rp * 64 + sr0) * 128 + aslot) = val;
    }
    __syncthreads();   // tile ready (drains vmcnt + lgkmcnt)

    int r = lane & 15, g = lane >> 4, l7 = lane & 7;
#pragma unroll
    for (int ks = 0; ks < 2; ++ks) {
      u32 ch = (u32)((g + ks * 4) ^ l7) * 16;
      bf16x8 af[4], bfv[4];
#pragma unroll
      for (int m = 0; m < 4; ++m)
        af[m] = *(const bf16x8*)((const char*)As + (wm * 64 + m * 16 + r) * 128 + ch);
#pragma unroll
      for (int n = 0; n < 4; ++n)
        bfv[n] = *(const bf16x8*)((const char*)Bs + (wn * 64 + n * 16 + r) * 128 + ch);
#pragma unroll
      for (int m = 0; m < 4; ++m)
#pragma unroll
        for (int n = 0; n < 4; ++n)
          acc[m][n] = __builtin_amdgcn_mfma_f32_16x16x32_bf16(bfv[n], af[m], acc[m][n], 0, 0, 0);
    }
  }

  // epilogue (swapped layout): row = m*16+(lane&15), cols = n*16+(lane>>4)*4+rr
  int m16 = lane & 15, ng4 = (lane >> 4) << 2;
#pragma unroll
  for (int m = 0; m < 4; ++m)
#pragma unroll
    for (int n = 0; n < 4; ++n) {
      size_t row = mbase + wm * 64 + m * 16 + m16;
      int colb = nbase + wn * 64 + n * 16 + ng4;
      float4 bv = *(const float4*)&bias[colb];
      uint2 val;
      val.x = pkbf(acc[m][n][0] + bv.x, acc[m][n][1] + bv.y);
      val.y = pkbf(acc[m][n][2] + bv.z, acc[m][n][3] + bv.w);
      *(uint2*)&Cout[row * (size_t)N + colb] = val;
    }
}

// ---------------- GEMM (R9 staging; swapped-operand epilogue) ----------------
__global__ __launch_bounds__(512) void k_gemm(const u16* __restrict__ A,
                                              const u16* __restrict__ Bt,
                                              const float* __restrict__ bias,
                                              void* __restrict__ Cout,
                                              int N, int out_bf16) {
  __shared__ u16 As[256 * 64];
  __shared__ u16 Bs[128 * 64];
  int nt = N >> 7;
  int nwg = gridDim.x;
  int bid = blockIdx.x;
  int swz = (bid & 7) * (nwg >> 3) + (bid >> 3);
  int mt = swz / nt;
  int ntile = swz - mt * nt;
  int tid = threadIdx.x;
  int lane = tid & 63, wid = tid >> 6;
  int wm = wid >> 1, wn = wid & 1;
  size_t mbase = (size_t)mt << 8;
  int nbase = ntile << 7;

  int srow = lane >> 3;
  u32 schunk = ((u32)(lane & 7)) ^ ((u32)srow);
  const u16* agS = A + (mbase + (size_t)(wid * 32 + srow)) * 256 + schunk * 8;
  const u16* bgS = Bt + ((size_t)(nbase + wid * 16 + srow)) * 256 + schunk * 8;

  f32x4 acc[4][4] = {};

#pragma unroll
  for (int kb = 0; kb < 4; ++kb) {
    __syncthreads();
#pragma unroll
    for (int it = 0; it < 4; ++it)
      glds16(agS + (size_t)(it * 8) * 256 + kb * 64, As + (wid * 32 + it * 8) * 64);
#pragma unroll
    for (int it = 0; it < 2; ++it)
      glds16(bgS + (size_t)(it * 8) * 256 + kb * 64, Bs + (wid * 16 + it * 8) * 64);
    __syncthreads();

    int r = lane & 15, g = lane >> 4, l7 = lane & 7;
#pragma unroll
    for (int ks = 0; ks < 2; ++ks) {
      u32 ch = (u32)((g + ks * 4) ^ l7) * 16;
      bf16x8 af[4], bfv[4];
#pragma unroll
      for (int m = 0; m < 4; ++m)
        af[m] = *(const bf16x8*)((const char*)As + (wm * 64 + m * 16 + r) * 128 + ch);
#pragma unroll
      for (int n = 0; n < 4; ++n)
        bfv[n] = *(const bf16x8*)((const char*)Bs + (wn * 64 + n * 16 + r) * 128 + ch);
#pragma unroll
      for (int m = 0; m < 4; ++m)
#pragma unroll
        for (int n = 0; n < 4; ++n)
          acc[m][n] = __builtin_amdgcn_mfma_f32_16x16x32_bf16(bfv[n], af[m], acc[m][n], 0, 0, 0);
    }
  }

  int m16 = lane & 15, ng4 = (lane >> 4) << 2;
#pragma unroll
  for (int m = 0; m < 4; ++m)
#pragma unroll
    for (int n = 0; n < 4; ++n) {
      size_t row = mbase + wm * 64 + m * 16 + m16;
      int colb = nbase + wn * 64 + n * 16 + ng4;
      float4 bv = *(const float4*)&bias[colb];
      if (out_bf16) {
        uint2 val;
        val.x = pkbf(acc[m][n][0] + bv.x, acc[m][n][1] + bv.y);
        val.y = pkbf(acc[m][n][2] + bv.z, acc[m][n][3] + bv.w);
        *(uint2*)&((u16*)Cout)[row * (size_t)N + colb] = val;
      } else {
        float4 vv;
        vv.x = acc[m][n][0] + bv.x;
        vv.y = acc[m][n][1] + bv.y;
        vv.z = acc[m][n][2] + bv.z;
        vv.w = acc[m][n][3] + bv.w;
        *(float4*)&((float*)Cout)[row * (size_t)N + colb] = vv;
      }
    }
}

// ---------------- attention + LePE (R9 VERIFIED version, unchanged) ----------------
__global__ __launch_bounds__(512) void k_attn(const u16* __restrict__ QKV,
                                              const float* __restrict__ lepe_w,
                                              const float* __restrict__ lepe_b,
                                              u16* __restrict__ Obuf) {
  __shared__ u16 BUF[4][128 * 64];   // 0:K 1:Vo 2:Vm 3:Vp, row-major [p][c], swizzled
  __shared__ float Mf[8][16][16];    // per-wave partial M (f32)
  __shared__ u16 Mt[4][16][32];      // M^T bf16, K-padded to 32
  __shared__ float lwS[9][16];
  __shared__ float lbS[16];

  int bid = blockIdx.x;
  int t = bid & 127, b = (bid >> 7) & 3, d = bid >> 9;
  int tid = threadIdx.x;
  int w = tid >> 6, l = tid & 63;
  int hh = w & 3, ph = w >> 2;

  ((u32*)Mt)[tid] = 0;
  ((u32*)Mt)[tid + 512] = 0;
  if (tid < 144) lwS[tid >> 4][tid & 15] = lepe_w[(tid & 15) * 9 + (tid >> 4)];
  if (tid < 16) lbS[tid] = lepe_b[tid];

  auto pixof = [&](int line, int p) -> u32 {
    int h, ww;
    if (d == 2)      { h = line; ww = p; }
    else if (d == 0) { h = p; ww = (line - (p + 1)) & 127; }
    else if (d == 1) { h = p; ww = (line + (p + 1)) & 127; }
    else             { h = p; ww = line; }
    return ((u32)(b * 128 + h) << 7) + (u32)ww;
  };

  // ---- Q prefetch into regs ----
  uint4 qreg[4];
  u32 qch = (u32)d * 64 + (u32)hh * 16 + (u32)((l >> 4) & 1) * 8;
#pragma unroll
  for (int k = 0; k < 4; ++k) {
    int p = (ph * 4 + k) * 16 + (l & 15);
    qreg[k] = *(const uint4*)(QKV + (u64)pixof(t, p) * 768 + qch);
  }

  // ---- stage via global_load_lds, source chunk pre-swizzled ----
  {
    int bf = w & 3;
    int line = t;
    u32 choff = (bf == 0) ? (256u + d * 64) : (512u + d * 64);
    bool ok = true;
    if (bf == 2) { line = t - 16; ok = (t >> 4) > 0; }
    if (bf == 3) { line = t + 16; ok = (t >> 4) < 7; }
    u16* Bb = &BUF[bf][0];
    int phh = (w >> 2) * 64;
#pragma unroll
    for (int it = 0; it < 8; ++it) {
      int p0 = phh + it * 8;   // wave-uniform
      if (ok) {
        int row = p0 + (l >> 3);
        u32 chunkx = ((u32)(l & 7)) ^ (((u32)row >> 2) & 7);
        const u16* g = QKV + (u64)pixof(line, row) * 768 + choff + chunkx * 8;
        glds16(g, Bb + p0 * 64);
      } else {
        *(uint4*)(Bb + p0 * 64 + l * 8) = make_uint4(0, 0, 0, 0);
      }
    }
  }
  __syncthreads();

  // ---- phase 1: wave w = (head hh, p-half ph): partial M = K^T V ----
  {
    u32 cb = ((u32)hh * 16 + (u32)(l & 15)) * 2;   // byte-in-row
    f32x4 m = {0.f, 0.f, 0.f, 0.f};
#pragma unroll
    for (int kc = 0; kc < 2; ++kc) {
      u32 pc = (u32)ph * 64 + (u32)kc * 32 + (u32)(l >> 4) * 8;
      union { u16 e[8]; bf16x8 v; } ka, vb;
#pragma unroll
      for (int e = 0; e < 8; ++e) {
        u32 row = pc + e;
        u32 addr = row * 128 + (cb ^ (((row >> 2) & 7) << 4));
        ka.e[e] = *(const u16*)((const char*)&BUF[0][0] + addr);
        vb.e[e] = *(const u16*)((const char*)&BUF[1][0] + addr);
      }
      m = __builtin_amdgcn_mfma_f32_16x16x32_bf16(ka.v, vb.v, m, 0, 0, 0);
    }
    *(f32x4*)&Mf[w][l & 15][(l >> 4) * 4] = m;
  }
  __syncthreads();

  // ---- combine halves -> Mt bf16 ----
  if (tid < 256) {
    int ch = tid >> 6;
    int c2 = (tid >> 2) & 15;
    int c1g = (tid & 3) * 4;
    f32x4 a = *(const f32x4*)&Mf[ch][c2][c1g];
    f32x4 bb = *(const f32x4*)&Mf[ch + 4][c2][c1g];
    u16* dst = &Mt[ch][c2][c1g];
    dst[0] = f2bf(a[0] + bb[0]);
    dst[1] = f2bf(a[1] + bb[1]);
    dst[2] = f2bf(a[2] + bb[2]);
    dst[3] = f2bf(a[3] + bb[3]);
  }
  __syncthreads();

  // ---- phase 2: O = Q*M + LePE conv + permuted store ----
  union UB { uint4 u; bf16x8 v; } mb;
  mb.u = *(const uint4*)((const char*)Mt + (u32)hh * 1024 + (u32)(l & 15) * 64 +
                         (u32)(l >> 4) * 16);

  float wreg[9];
#pragma unroll
  for (int k = 0; k < 9; ++k) wreg[k] = lwS[k][l & 15];
  float lbias = lbS[l & 15];
  int nf = (t >> 2) & 3;
  int tp = (t & 112) | ((t & 3) << 2) | hh;
  u32 och = (u32)d * 64 + (u32)nf * 16 + (u32)(l & 15);
  u32 ccb2 = ((u32)hh * 16 + (u32)(l & 15)) * 2;  // byte-in-row
  int g = l >> 4;

#pragma unroll
  for (int k = 0; k < 4; ++k) {
    int pt = ph * 4 + k;
    union UA { uint4 u; bf16x8 v; } qa;
    qa.u = qreg[k];
    f32x4 o = {0.f, 0.f, 0.f, 0.f};
    o = __builtin_amdgcn_mfma_f32_16x16x32_bf16(qa.v, mb.v, o, 0, 0, 0);

    int p0 = pt * 16 + g * 4;
    float tap[3][6];
    const u32 bufid[3] = {2u, 1u, 3u};
#pragma unroll
    for (int r = 0; r < 3; ++r) {
      const char* Bp = (const char*)&BUF[bufid[r]][0];
#pragma unroll
      for (int j = 0; j < 6; ++j) {
        int pr = p0 - 1 + j;
        bool okr = (pr >= 0) && (pr < 128);
        u32 row = (u32)(okr ? pr : 0);
        u32 addr = row * 128 + (ccb2 ^ (((row >> 2) & 7) << 4));
        tap[r][j] = okr ? bf2f(*(const u16*)(Bp + addr)) : 0.f;
      }
    }
#pragma unroll
    for (int rr = 0; rr < 4; ++rr) {
      float acc = o[rr] + lbias;
#pragma unroll
      for (int r = 0; r < 3; ++r)
#pragma unroll
        for (int bb = 0; bb < 3; ++bb)
          acc += wreg[r * 3 + bb] * tap[r][rr + bb];
      int p = p0 + rr;
      int ho, wo;
      if (d == 2)      { ho = tp; wo = p; }
      else if (d == 0) { ho = p; wo = (tp - (p + 1)) & 127; }
      else if (d == 1) { ho = p; wo = (tp + (p + 1)) & 127; }
      else             { ho = p; wo = tp; }
      u32 opix = ((u32)(b * 128 + ho) << 7) + (u32)wo;
      Obuf[opix * 256 + och] = f2bf(acc);
    }
  }
}

// ---------------- launch ----------------
extern "C" void kernel_launch(void* const* d_in, const int* in_sizes, int n_in,
                              void* d_out, int out_size, void* d_ws, size_t ws_size,
                              hipStream_t stream) {
  (void)in_sizes; (void)n_in; (void)out_size; (void)ws_size;
  const float* x     = (const float*)d_in[0];
  const float* Wq    = (const float*)d_in[1];
  const float* bq    = (const float*)d_in[2];
  const float* Wkv   = (const float*)d_in[3];
  const float* bkv   = (const float*)d_in[4];
  const float* Wproj = (const float*)d_in[5];
  const float* bproj = (const float*)d_in[6];
  const float* lepe_w = (const float*)d_in[7];
  const float* lepe_b = (const float*)d_in[8];
  float* out = (float*)d_out;

  char* ws = (char*)d_ws;
  u16* QKV   = (u16*)(ws + 33554432);    //  65536x768 bf16 = 96 MB
  u16* Obuf  = (u16*)(ws + 134217728);   //  65536x256 bf16 = 32 MB
  u16* W1t   = (u16*)(ws + 167772160);   //  768x256 bf16
  u16* Wpt   = (u16*)(ws + 168165376);   //  256x256 bf16
  float* b1  = (float*)(ws + 168296448); //  768 f32

  k_prep_w<<<1024, 256, 0, stream>>>(Wq, bq, Wkv, bkv, Wproj, W1t, b1, Wpt);
  k_gemm1f<<<256 * 6, 512, 0, stream>>>(x, W1t, b1, QKV);
  k_attn<<<2048, 512, 0, stream>>>(QKV, lepe_w, lepe_b, Obuf);
  k_gemm<<<256 * 2, 512, 0, stream>>>(Obuf, Wpt, bproj, out, 256, 0);
}

// Round 14
// 114.013 us; speedup vs baseline: 1.2135x; 1.2135x over previous
//
#include <hip/hip_runtime.h>

typedef unsigned short u16;
typedef unsigned int u32;
typedef unsigned long long u64;
typedef __bf16 bf16x8 __attribute__((ext_vector_type(8)));
typedef float f32x4 __attribute__((ext_vector_type(4)));

__device__ __forceinline__ u16 f2bf(float f) {
  u32 u = __float_as_uint(f);
  return (u16)((u + 0x7fffu + ((u >> 16) & 1u)) >> 16);  // RNE
}
__device__ __forceinline__ float bf2f(u16 h) {
  return __uint_as_float(((u32)h) << 16);
}
// packed f32x2 -> bf16x2 (one instruction, RNE)
__device__ __forceinline__ u32 pkbf(float lo, float hi) {
  u32 r;
  asm("v_cvt_pk_bf16_f32 %0, %1, %2" : "=v"(r) : "v"(lo), "v"(hi));
  return r;
}

// async global->LDS, 16B per lane; LDS dest = wave-uniform base + lane*16,
// global src is PER-LANE (verified R5/R6)
__device__ __forceinline__ void glds16(const void* g, void* s) {
  __builtin_amdgcn_global_load_lds(
      (__attribute__((address_space(1))) void*)(u64)g,
      (__attribute__((address_space(3))) void*)(u32)(u64)s, 16, 0, 0);
}

// ---------------- weight prep ----------------
__global__ __launch_bounds__(256) void k_prep_w(
    const float* __restrict__ Wq, const float* __restrict__ bq,
    const float* __restrict__ Wkv, const float* __restrict__ bkv,
    const float* __restrict__ Wproj,
    u16* __restrict__ W1t, float* __restrict__ b1, u16* __restrict__ Wpt) {
  int n = blockIdx.x, k = threadIdx.x;
  if (n < 768) {
    float v = (n < 256) ? Wq[k * 256 + n] * 0.125f : Wkv[k * 512 + (n - 256)];
    W1t[n * 256 + k] = f2bf(v);
    if (k == 0) b1[n] = (n < 256) ? bq[n] * 0.125f : bkv[n - 256];
  } else {
    int nn = n - 768;
    Wpt[nn * 256 + k] = f2bf(Wproj[k * 256 + nn]);
  }
}

// ---------------- GEMM1 fused (R10 VERIFIED version, unchanged) ----------------
__global__ __launch_bounds__(512) void k_gemm1f(const float* __restrict__ A,
                                                const u16* __restrict__ Bt,
                                                const float* __restrict__ bias,
                                                u16* __restrict__ Cout) {
  __shared__ u16 As[256 * 64];   // 32 KB
  __shared__ u16 Bs[128 * 64];   // 16 KB
  const int N = 768, nt = 6;
  int nwg = gridDim.x;
  int bid = blockIdx.x;
  int swz = (bid & 7) * (nwg >> 3) + (bid >> 3);
  int mt = swz / nt;
  int ntile = swz - mt * nt;
  int tid = threadIdx.x;
  int lane = tid & 63, wid = tid >> 6;
  int wm = wid >> 1, wn = wid & 1;
  size_t mbase = (size_t)mt << 8;
  int nbase = ntile << 7;

  int srow = lane >> 3;
  u32 schunk = ((u32)(lane & 7)) ^ ((u32)srow);
  const u16* bgS = Bt + ((size_t)(nbase + wid * 16 + srow)) * 256 + schunk * 8;

  int sc = tid & 7;
  int sr0 = tid >> 3;            // 0..63
  u32 aslot = (((u32)sc ^ ((u32)sr0 & 7)) * 16);
  const float* agS = A + (mbase + (size_t)sr0) * 256 + sc * 8;

  f32x4 acc[4][4] = {};

#pragma unroll
  for (int kb = 0; kb < 4; ++kb) {
    __syncthreads();
#pragma unroll
    for (int it = 0; it < 2; ++it)
      glds16(bgS + (size_t)(it * 8) * 256 + kb * 64, Bs + (wid * 16 + it * 8) * 64);
#pragma unroll
    for (int rp = 0; rp < 4; ++rp) {
      const float* src = agS + (size_t)(rp * 64) * 256 + kb * 64;
      float4 f0 = *(const float4*)(src);
      float4 f1 = *(const float4*)(src + 4);
      uint4 val;
      val.x = pkbf(f0.x, f0.y);
      val.y = pkbf(f0.z, f0.w);
      val.z = pkbf(f1.x, f1.y);
      val.w = pkbf(f1.z, f1.w);
      *(uint4*)((char*)As + (rp * 64 + sr0) * 128 + aslot) = val;
    }
    __syncthreads();

    int r = lane & 15, g = lane >> 4, l7 = lane & 7;
#pragma unroll
    for (int ks = 0; ks < 2; ++ks) {
      u32 ch = (u32)((g + ks * 4) ^ l7) * 16;
      bf16x8 af[4], bfv[4];
#pragma unroll
      for (int m = 0; m < 4; ++m)
        af[m] = *(const bf16x8*)((const char*)As + (wm * 64 + m * 16 + r) * 128 + ch);
#pragma unroll
      for (int n = 0; n < 4; ++n)
        bfv[n] = *(const bf16x8*)((const char*)Bs + (wn * 64 + n * 16 + r) * 128 + ch);
#pragma unroll
      for (int m = 0; m < 4; ++m)
#pragma unroll
        for (int n = 0; n < 4; ++n)
          acc[m][n] = __builtin_amdgcn_mfma_f32_16x16x32_bf16(af[m], bfv[n], acc[m][n], 0, 0, 0);
    }
  }

  int cg4 = (lane >> 4) << 2;
  int cl = lane & 15;
#pragma unroll
  for (int m = 0; m < 4; ++m)
#pragma unroll
    for (int n = 0; n < 4; ++n) {
      size_t row0 = mbase + wm * 64 + m * 16 + cg4;
      int col = nbase + wn * 64 + n * 16 + cl;
      float bv = bias[col];
#pragma unroll
      for (int rr = 0; rr < 4; ++rr)
        Cout[(row0 + rr) * (size_t)N + col] = f2bf(acc[m][n][rr] + bv);
    }
}

// ---------------- GEMM (R9/R10 VERIFIED version, unchanged; used for GEMM2) ----------------
__global__ __launch_bounds__(512) void k_gemm(const u16* __restrict__ A,
                                              const u16* __restrict__ Bt,
                                              const float* __restrict__ bias,
                                              void* __restrict__ Cout,
                                              int N, int out_bf16) {
  __shared__ u16 As[256 * 64];
  __shared__ u16 Bs[128 * 64];
  int nt = N >> 7;
  int nwg = gridDim.x;
  int bid = blockIdx.x;
  int swz = (bid & 7) * (nwg >> 3) + (bid >> 3);
  int mt = swz / nt;
  int ntile = swz - mt * nt;
  int tid = threadIdx.x;
  int lane = tid & 63, wid = tid >> 6;
  int wm = wid >> 1, wn = wid & 1;
  size_t mbase = (size_t)mt << 8;
  int nbase = ntile << 7;

  int srow = lane >> 3;
  u32 schunk = ((u32)(lane & 7)) ^ ((u32)srow);
  const u16* agS = A + (mbase + (size_t)(wid * 32 + srow)) * 256 + schunk * 8;
  const u16* bgS = Bt + ((size_t)(nbase + wid * 16 + srow)) * 256 + schunk * 8;

  f32x4 acc[4][4] = {};

#pragma unroll
  for (int kb = 0; kb < 4; ++kb) {
    __syncthreads();
#pragma unroll
    for (int it = 0; it < 4; ++it)
      glds16(agS + (size_t)(it * 8) * 256 + kb * 64, As + (wid * 32 + it * 8) * 64);
#pragma unroll
    for (int it = 0; it < 2; ++it)
      glds16(bgS + (size_t)(it * 8) * 256 + kb * 64, Bs + (wid * 16 + it * 8) * 64);
    __syncthreads();

    int r = lane & 15, g = lane >> 4, l7 = lane & 7;
#pragma unroll
    for (int ks = 0; ks < 2; ++ks) {
      u32 ch = (u32)((g + ks * 4) ^ l7) * 16;
      bf16x8 af[4], bfv[4];
#pragma unroll
      for (int m = 0; m < 4; ++m)
        af[m] = *(const bf16x8*)((const char*)As + (wm * 64 + m * 16 + r) * 128 + ch);
#pragma unroll
      for (int n = 0; n < 4; ++n)
        bfv[n] = *(const bf16x8*)((const char*)Bs + (wn * 64 + n * 16 + r) * 128 + ch);
#pragma unroll
      for (int m = 0; m < 4; ++m)
#pragma unroll
        for (int n = 0; n < 4; ++n)
          acc[m][n] = __builtin_amdgcn_mfma_f32_16x16x32_bf16(af[m], bfv[n], acc[m][n], 0, 0, 0);
    }
  }

  int cg4 = (lane >> 4) << 2;
  int cl = lane & 15;
#pragma unroll
  for (int m = 0; m < 4; ++m)
#pragma unroll
    for (int n = 0; n < 4; ++n) {
      size_t row0 = mbase + wm * 64 + m * 16 + cg4;
      int col = nbase + wn * 64 + n * 16 + cl;
      float bv = bias[col];
#pragma unroll
      for (int rr = 0; rr < 4; ++rr) {
        float v = acc[m][n][rr] + bv;
        if (out_bf16) ((u16*)Cout)[(row0 + rr) * (size_t)N + col] = f2bf(v);
        else ((float*)Cout)[(row0 + rr) * (size_t)N + col] = v;
      }
    }
}

// ---------------- attention + LePE ----------------
// R9 staging/phase-1 (verified). Mt = M^T [head][c2][c1 padded to 32] — the
// R9-VERIFIED layout (R13's bug was transposing this write). Phase 2:
// o = mfma(Mt_frag, Q_frag, 0): A[c2][c1]=M^T (rows 16..31 of k zero), B=Q^T
// (col=pos=l&15, k=c1; garbage k>=16 lanes killed by zero A). D: lane gets
// O[c2=(l>>4)*4+rr][pos=l&15] -> 4 consecutive channels/lane => uint2 taps
// and packed uint2 stores.
__global__ __launch_bounds__(512) void k_attn(const u16* __restrict__ QKV,
                                              const float* __restrict__ lepe_w,
                                              const float* __restrict__ lepe_b,
                                              u16* __restrict__ Obuf) {
  __shared__ u16 BUF[4][128 * 64];   // 0:K 1:Vo 2:Vm 3:Vp, row-major [p][c], swizzled
  __shared__ float Mf[8][16][16];    // per-wave partial M (f32)
  __shared__ u16 Mt[4][16][32];      // M^T [head][c2][c1 padded to 32]
  __shared__ float lwS[9][16];
  __shared__ float lbS[16];

  int bid = blockIdx.x;
  int t = bid & 127, b = (bid >> 7) & 3, d = bid >> 9;
  int tid = threadIdx.x;
  int w = tid >> 6, l = tid & 63;
  int hh = w & 3, ph = w >> 2;

  ((u32*)Mt)[tid] = 0;
  ((u32*)Mt)[tid + 512] = 0;
  if (tid < 144) lwS[tid >> 4][tid & 15] = lepe_w[(tid & 15) * 9 + (tid >> 4)];
  if (tid < 16) lbS[tid] = lepe_b[tid];

  auto pixof = [&](int line, int p) -> u32 {
    int h, ww;
    if (d == 2)      { h = line; ww = p; }
    else if (d == 0) { h = p; ww = (line - (p + 1)) & 127; }
    else if (d == 1) { h = p; ww = (line + (p + 1)) & 127; }
    else             { h = p; ww = line; }
    return ((u32)(b * 128 + h) << 7) + (u32)ww;
  };

  // ---- Q prefetch into regs (R9 verified) ----
  uint4 qreg[4];
  u32 qch = (u32)d * 64 + (u32)hh * 16 + (u32)((l >> 4) & 1) * 8;
#pragma unroll
  for (int k = 0; k < 4; ++k) {
    int p = (ph * 4 + k) * 16 + (l & 15);
    qreg[k] = *(const uint4*)(QKV + (u64)pixof(t, p) * 768 + qch);
  }

  // ---- stage via global_load_lds, source chunk pre-swizzled (R9 verified) ----
  {
    int bf = w & 3;
    int line = t;
    u32 choff = (bf == 0) ? (256u + d * 64) : (512u + d * 64);
    bool ok = true;
    if (bf == 2) { line = t - 16; ok = (t >> 4) > 0; }
    if (bf == 3) { line = t + 16; ok = (t >> 4) < 7; }
    u16* Bb = &BUF[bf][0];
    int phh = (w >> 2) * 64;
#pragma unroll
    for (int it = 0; it < 8; ++it) {
      int p0 = phh + it * 8;   // wave-uniform
      if (ok) {
        int row = p0 + (l >> 3);
        u32 chunkx = ((u32)(l & 7)) ^ (((u32)row >> 2) & 7);
        const u16* g = QKV + (u64)pixof(line, row) * 768 + choff + chunkx * 8;
        glds16(g, Bb + p0 * 64);
      } else {
        *(uint4*)(Bb + p0 * 64 + l * 8) = make_uint4(0, 0, 0, 0);
      }
    }
  }
  __syncthreads();

  // ---- phase 1: wave w = (head hh, p-half ph): partial M = K^T V (R9 verified) ----
  {
    u32 cb = ((u32)hh * 16 + (u32)(l & 15)) * 2;   // byte-in-row
    f32x4 m = {0.f, 0.f, 0.f, 0.f};
#pragma unroll
    for (int kc = 0; kc < 2; ++kc) {
      u32 pc = (u32)ph * 64 + (u32)kc * 32 + (u32)(l >> 4) * 8;
      union { u16 e[8]; bf16x8 v; } ka, vb;
#pragma unroll
      for (int e = 0; e < 8; ++e) {
        u32 row = pc + e;
        u32 addr = row * 128 + (cb ^ (((row >> 2) & 7) << 4));
        ka.e[e] = *(const u16*)((const char*)&BUF[0][0] + addr);
        vb.e[e] = *(const u16*)((const char*)&BUF[1][0] + addr);
      }
      m = __builtin_amdgcn_mfma_f32_16x16x32_bf16(ka.v, vb.v, m, 0, 0, 0);
    }
    *(f32x4*)&Mf[w][l & 15][(l >> 4) * 4] = m;
  }
  __syncthreads();

  // ---- combine halves -> Mt = M^T[c2][c1] bf16 (R9 VERIFIED write) ----
  if (tid < 256) {
    int ch = tid >> 6;
    int c2 = (tid >> 2) & 15;
    int c1g = (tid & 3) * 4;
    f32x4 a = *(const f32x4*)&Mf[ch][c2][c1g];
    f32x4 bb2 = *(const f32x4*)&Mf[ch + 4][c2][c1g];
    u16* dst = &Mt[ch][c2][c1g];
    dst[0] = f2bf(a[0] + bb2[0]);
    dst[1] = f2bf(a[1] + bb2[1]);
    dst[2] = f2bf(a[2] + bb2[2]);
    dst[3] = f2bf(a[3] + bb2[3]);
  }
  __syncthreads();

  // ---- phase 2: O = Q*M via swapped MFMA + LePE conv + packed store ----
  // A-frag = M^T: lane l supplies A-row c2 = l&15, k-chunk c1 = (l>>4)*8..+7
  // (identical bytes to the R9 B-frag read — layout proven on HW).
  union UB { uint4 u; bf16x8 v; } mb;
  mb.u = *(const uint4*)((const char*)Mt + (u32)hh * 1024 + (u32)(l & 15) * 64 +
                         (u32)(l >> 4) * 16);

  int g = l >> 4;                 // channel quad: lane owns c2 = 4g+rr
  float4 w4[9];
#pragma unroll
  for (int kk = 0; kk < 9; ++kk) w4[kk] = *(const float4*)&lwS[kk][g * 4];
  float4 lb4 = *(const float4*)&lbS[g * 4];
  int nf = (t >> 2) & 3;
  int tp = (t & 112) | ((t & 3) << 2) | hh;
  u32 och2 = (u32)d * 64 + (u32)nf * 16 + (u32)g * 4;
  u32 cbyte = (u32)hh * 32 + (u32)g * 8;   // 4-ch byte offset in BUF row
  const u32 bufid[3] = {2u, 1u, 3u};       // r=0: t-16, r=1: t, r=2: t+16

#pragma unroll
  for (int k = 0; k < 4; ++k) {
    union UA { uint4 u; bf16x8 v; } qa;
    qa.u = qreg[k];
    f32x4 o = {0.f, 0.f, 0.f, 0.f};
    o = __builtin_amdgcn_mfma_f32_16x16x32_bf16(mb.v, qa.v, o, 0, 0, 0);
    int pos = (ph * 4 + k) * 16 + (l & 15);
    float a0 = o[0] + lb4.x, a1 = o[1] + lb4.y;
    float a2 = o[2] + lb4.z, a3 = o[3] + lb4.w;
#pragma unroll
    for (int r = 0; r < 3; ++r) {
      const char* Bp = (const char*)&BUF[bufid[r]][0];
#pragma unroll
      for (int bb = 0; bb < 3; ++bb) {
        int row = pos + bb - 1;
        bool okr = (row >= 0) && (row < 128);
        u32 rw = (u32)(okr ? row : 0);
        u32 addr = rw * 128 + (cbyte ^ (((rw >> 2) & 7) << 4));
        union { uint2 u2; u16 e[4]; } tv;
        tv.u2 = okr ? *(const uint2*)(Bp + addr) : make_uint2(0u, 0u);
        float4 wv = w4[r * 3 + bb];
        a0 += wv.x * bf2f(tv.e[0]);
        a1 += wv.y * bf2f(tv.e[1]);
        a2 += wv.z * bf2f(tv.e[2]);
        a3 += wv.w * bf2f(tv.e[3]);
      }
    }
    int ho, wo;
    if (d == 2)      { ho = tp; wo = pos; }
    else if (d == 0) { ho = pos; wo = (tp - (pos + 1)) & 127; }
    else if (d == 1) { ho = pos; wo = (tp + (pos + 1)) & 127; }
    else             { ho = pos; wo = tp; }
    u32 opix = ((u32)(b * 128 + ho) << 7) + (u32)wo;
    uint2 val;
    val.x = pkbf(a0, a1);
    val.y = pkbf(a2, a3);
    *(uint2*)&Obuf[opix * 256 + och2] = val;
  }
}

// ---------------- launch ----------------
extern "C" void kernel_launch(void* const* d_in, const int* in_sizes, int n_in,
                              void* d_out, int out_size, void* d_ws, size_t ws_size,
                              hipStream_t stream) {
  (void)in_sizes; (void)n_in; (void)out_size; (void)ws_size;
  const float* x     = (const float*)d_in[0];
  const float* Wq    = (const float*)d_in[1];
  const float* bq    = (const float*)d_in[2];
  const float* Wkv   = (const float*)d_in[3];
  const float* bkv   = (const float*)d_in[4];
  const float* Wproj = (const float*)d_in[5];
  const float* bproj = (const float*)d_in[6];
  const float* lepe_w = (const float*)d_in[7];
  const float* lepe_b = (const float*)d_in[8];
  float* out = (float*)d_out;

  char* ws = (char*)d_ws;
  u16* QKV   = (u16*)(ws + 33554432);    //  65536x768 bf16 = 96 MB
  u16* Obuf  = (u16*)(ws + 134217728);   //  65536x256 bf16 = 32 MB
  u16* W1t   = (u16*)(ws + 167772160);   //  768x256 bf16
  u16* Wpt   = (u16*)(ws + 168165376);   //  256x256 bf16
  float* b1  = (float*)(ws + 168296448); //  768 f32

  k_prep_w<<<1024, 256, 0, stream>>>(Wq, bq, Wkv, bkv, Wproj, W1t, b1, Wpt);
  k_gemm1f<<<256 * 6, 512, 0, stream>>>(x, W1t, b1, QKV);
  k_attn<<<2048, 512, 0, stream>>>(QKV, lepe_w, lepe_b, Obuf);
  k_gemm<<<256 * 2, 512, 0, stream>>>(Obuf, Wpt, bproj, out, 256, 0);
}